// Round 7
// baseline (14.781 us; speedup 1.0000x reference)
//
#include <hip/hip_runtime.h>
#include <math.h>

#define NN 1024
#define HH 512
#define BB 64
#define NT 512    // 8 waves -> 2 waves/SIMD
#define MAGIC 0x5A5A5A5Au

__global__ __launch_bounds__(NT) void lfl_fused(const float* __restrict__ scores,
                                                const float* __restrict__ labels,
                                                float* __restrict__ out,
                                                unsigned long long* __restrict__ slots) {
    __shared__ float4 kv[2][NT];    // (k0,v0,k1,v1) per thread, double-buffered
    __shared__ float osc_l[NN];
    __shared__ float sa_l[NN];
    __shared__ float sb_l[NN];
    __shared__ float wA[8], wB[8];

    const int b    = blockIdx.x;
    const int t    = threadIdx.x;
    const int lane = t & 63;
    const int wv   = t >> 6;

    // elements e = 2t, 2t+1; key = -label (ascending == argsort(-labels)), payload = score
    const float2 lb2 = *reinterpret_cast<const float2*>(&labels[b * NN + 2 * t]);
    const float2 sc2 = *reinterpret_cast<const float2*>(&scores[b * NN + 2 * t]);
    float k0 = -lb2.x, k1 = -lb2.y;
    float v0 = sc2.x,  v1 = sc2.y;

    auto ce_intra = [&](bool up) {   // element stride 1 within thread
        bool sw = up ? (k0 > k1) : (k0 < k1);
        if (sw) { float tk = k0; k0 = k1; k1 = tk; float tv = v0; v0 = v1; v1 = tv; }
    };
    auto ce_shfl = [&](int ts, bool up) {   // thread stride ts (element stride 2*ts)
        bool lower = ((t & ts) == 0);
        bool cond  = (up == lower);
        float kp0 = __shfl_xor(k0, ts), vp0 = __shfl_xor(v0, ts);
        float kp1 = __shfl_xor(k1, ts), vp1 = __shfl_xor(v1, ts);
        bool g0 = cond ? (kp0 < k0) : (kp0 > k0);
        bool g1 = cond ? (kp1 < k1) : (kp1 > k1);
        if (g0) { k0 = kp0; v0 = vp0; }
        if (g1) { k1 = kp1; v1 = vp1; }
    };
    int pb = 0;
    auto ce_lds = [&](int ts, bool up) {    // thread stride ts >= 64 via LDS, 1 barrier
        kv[pb][t] = make_float4(k0, v0, k1, v1);
        __syncthreads();
        float4 q = kv[pb][t ^ ts];
        bool lower = ((t & ts) == 0);
        bool cond  = (up == lower);
        bool g0 = cond ? (q.x < k0) : (q.x > k0);
        bool g1 = cond ? (q.z < k1) : (q.z > k1);
        if (g0) { k0 = q.x; v0 = q.y; }
        if (g1) { k1 = q.z; v1 = q.w; }
        pb ^= 1;
    };

    // ---- Bitonic sort, ascending on k; up = ((t & (S>>1)) == 0) ----
    ce_intra((t & 1) == 0);                       // S=2
    #pragma unroll
    for (int S = 4; S <= 128; S <<= 1) {          // all intra-wave
        bool up = ((t & (S >> 1)) == 0);
        #pragma unroll
        for (int ts = S >> 2; ts >= 1; ts >>= 1) ce_shfl(ts, up);
        ce_intra(up);
    }
    {   // S=256
        bool up = ((t & 128) == 0);
        ce_lds(64, up);
        #pragma unroll
        for (int ts = 32; ts >= 1; ts >>= 1) ce_shfl(ts, up);
        ce_intra(up);
    }
    {   // S=512
        bool up = ((t & 256) == 0);
        ce_lds(128, up);
        ce_lds(64, up);
        #pragma unroll
        for (int ts = 32; ts >= 1; ts >>= 1) ce_shfl(ts, up);
        ce_intra(up);
    }
    {   // S=1024 (up always true for t<512)
        ce_lds(256, true);
        ce_lds(128, true);
        ce_lds(64, true);
        #pragma unroll
        for (int ts = 32; ts >= 1; ts >>= 1) ce_shfl(ts, true);
        ce_intra(true);
    }
    // thread t holds sorted elements 2t (k0,v0) and 2t+1 (k1,v1); osc = v

    // ---- Suffix scans of e^{osc}, e^{-osc} ----
    float a0 = __expf(v0),  a1 = __expf(v1);
    float e0 = __expf(-v0), e1 = __expf(-v1);
    float Ta = a0 + a1, Tb = e0 + e1;   // thread totals
    float Sa = Ta, Sb = Tb;
    #pragma unroll
    for (int d = 1; d < 64; d <<= 1) {
        float xa = __shfl_down(Sa, d);
        float xb = __shfl_down(Sb, d);
        if (lane + d < 64) { Sa += xa; Sb += xb; }
    }
    if (lane == 0) { wA[wv] = Sa; wB[wv] = Sb; }
    __syncthreads();
    float addA = 0.f, addB = 0.f;
    for (int w = wv + 1; w < 8; ++w) { addA += wA[w]; addB += wB[w]; }
    float saE0 = Sa + addA;        // inclusive suffix at element 2t
    float sbE0 = Sb + addB;

    // ---- Publish per-element arrays ----
    osc_l[2 * t]     = v0;
    osc_l[2 * t + 1] = v1;
    sa_l[2 * t]      = saE0;
    sa_l[2 * t + 1]  = saE0 - a0;
    sb_l[2 * t]      = sbE0;
    sb_l[2 * t + 1]  = sbE0 - e0;
    __syncthreads();

    // ---- Per-j term: j = t (all 512 threads active) ----
    float P = sa_l[t] - sa_l[513];           // sum_{n=j}^{512} e^{osc[n]}
    float T = sb_l[511 + t];                 // sum_{k=511+j}^{1023} e^{-osc[k]}
    float denom = P * T - (t == 0 ? 2.0f : (t == 1 ? 1.0f : 0.0f));
    float acc = (osc_l[t] - osc_l[NN - 1 - t]) - __logf(denom);

    // ---- Block reduce ----
    #pragma unroll
    for (int off = 32; off > 0; off >>= 1) acc += __shfl_down(acc, off);
    if (lane == 0) wA[wv] = acc;
    __syncthreads();

    float part = 0.f;
    if (t == 0) {
        #pragma unroll
        for (int w = 0; w < 8; ++w) part += wA[w];
        if (b != 0) {
            // self-validating publish: {bits^MAGIC, bits} — 0xAA poison never validates
            unsigned lo = __float_as_uint(part);
            unsigned long long pk = ((unsigned long long)(lo ^ MAGIC) << 32) | (unsigned long long)lo;
            atomicExch(&slots[b], pk);       // device-scope RMW, visible cross-XCD
        }
    }

    // ---- Block 0, wave 0: gather 63 partials, write scalar ----
    if (b == 0 && t < 64) {
        float x = (t == 0) ? part : 0.f;
        if (t > 0) {
            unsigned long long pk;
            do {
                pk = atomicAdd(&slots[t], 0ULL);   // device-scope atomic read
            } while ((unsigned)(pk >> 32) != ((unsigned)pk ^ MAGIC));
            x = __uint_as_float((unsigned)pk);
        }
        #pragma unroll
        for (int off = 32; off > 0; off >>= 1) x += __shfl_down(x, off);
        if (t == 0) out[0] = -x / (float)BB;
    }
}

extern "C" void kernel_launch(void* const* d_in, const int* in_sizes, int n_in,
                              void* d_out, int out_size, void* d_ws, size_t ws_size,
                              hipStream_t stream) {
    const float* scores = (const float*)d_in[0];
    const float* labels = (const float*)d_in[1];
    float* out = (float*)d_out;
    unsigned long long* slots = (unsigned long long*)d_ws;

    lfl_fused<<<BB, NT, 0, stream>>>(scores, labels, out, slots);
}

// Round 8
// 14.302 us; speedup vs baseline: 1.0335x; 1.0335x over previous
//
#include <hip/hip_runtime.h>
#include <math.h>

#define NN 1024
#define HH 512
#define BB 64
#define NT 1024   // 16 waves -> 4 waves/SIMD: best measured latency hiding (R4/R7 show fewer waves hurt)
#define MAGIC 0x5A5A5A5Au

__global__ __launch_bounds__(NT) void lfl_fused(const float* __restrict__ scores,
                                                const float* __restrict__ labels,
                                                float* __restrict__ out,
                                                unsigned long long* __restrict__ slots) {
    __shared__ float2 kv[2][NN];    // double-buffered packed (key,score)
    __shared__ float osc_l[NN];
    __shared__ float sa_l[NN];
    __shared__ float sb_l[NN];
    __shared__ float wA[16], wB[16];

    const int b    = blockIdx.x;
    const int t    = threadIdx.x;
    const int lane = t & 63;
    const int wv   = t >> 6;

    // key = -label (ascending == descending label == argsort(-labels)), payload = score
    float k = -labels[b * NN + t];
    float v = scores[b * NN + t];

    auto shfl_ce = [&](int stride, bool up) {
        float kp = __shfl_xor(k, stride);
        float vp = __shfl_xor(v, stride);
        bool lower = ((t & stride) == 0);
        bool take  = (up == lower) ? (kp < k) : (kp > k);   // strict: ties never swap
        if (take) { k = kp; v = vp; }
    };

    int pb = 0;
    auto lds_ex = [&](int stride, bool up) {
        kv[pb][t] = make_float2(k, v);
        __syncthreads();                       // single barrier: next round uses other buffer
        float2 p = kv[pb][t ^ stride];
        bool lower = ((t & stride) == 0);
        bool take  = (up == lower) ? (p.x < k) : (p.x > k);
        if (take) { k = p.x; v = p.y; }
        pb ^= 1;
    };

    // ---- Bitonic sort, ascending on k ----
    #pragma unroll
    for (int size = 2; size <= 64; size <<= 1) {
        bool up = ((t & size) == 0);
        #pragma unroll
        for (int s = size >> 1; s >= 1; s >>= 1) shfl_ce(s, up);
    }
    #pragma unroll
    for (int size = 128; size <= 1024; size <<= 1) {
        bool up = ((t & size) == 0);           // size=1024: always true
        for (int s = size >> 1; s >= 64; s >>= 1) lds_ex(s, up);
        #pragma unroll
        for (int s = 32; s >= 1; s >>= 1) shfl_ce(s, up);
    }
    // thread t holds sorted element t: osc[t] = v

    // ---- Suffix scans of e^{osc}, e^{-osc} ----
    float Sa = __expf(v);
    float Sb = __expf(-v);
    #pragma unroll
    for (int d = 1; d < 64; d <<= 1) {
        float xa = __shfl_down(Sa, d);
        float xb = __shfl_down(Sb, d);
        if (lane + d < 64) { Sa += xa; Sb += xb; }
    }
    if (lane == 0) { wA[wv] = Sa; wB[wv] = Sb; }
    __syncthreads();
    float addA = 0.f, addB = 0.f;
    for (int w = wv + 1; w < 16; ++w) { addA += wA[w]; addB += wB[w]; }
    float sa = Sa + addA;   // inclusive suffix sum of e^{osc} at index t
    float sb = Sb + addB;   // inclusive suffix sum of e^{-osc} at index t

    // ---- Publish ----
    osc_l[t] = v;
    sa_l[t]  = sa;
    sb_l[t]  = sb;
    __syncthreads();

    // ---- Per-j term (j = t < 512) ----
    float acc = 0.f;
    if (t < HH) {
        float P = sa - sa_l[513];               // sum_{n=j}^{512} e^{osc[n]}
        float T = sb_l[511 + t];                // sum_{k=511+j}^{1023} e^{-osc[k]}
        float denom = P * T - (t == 0 ? 2.0f : (t == 1 ? 1.0f : 0.0f));
        acc = (v - osc_l[NN - 1 - t]) - __logf(denom);
    }

    // ---- Block reduce ----
    #pragma unroll
    for (int off = 32; off > 0; off >>= 1) acc += __shfl_down(acc, off);
    if (lane == 0) wA[wv] = acc;
    __syncthreads();

    float part = 0.f;
    if (t == 0) {
        #pragma unroll
        for (int w = 0; w < 16; ++w) part += wA[w];
        if (b != 0) {
            // self-validating publish: {bits^MAGIC, bits} — 0xAA poison never validates
            unsigned lo = __float_as_uint(part);
            unsigned long long pk = ((unsigned long long)(lo ^ MAGIC) << 32) | (unsigned long long)lo;
            atomicExch(&slots[b], pk);          // device-scope RMW -> visible cross-XCD
        }
    }

    // ---- Block 0, wave 0: gather the other 63 partials and write out ----
    if (b == 0 && t < 64) {
        float x = (t == 0) ? part : 0.f;
        if (t > 0) {
            unsigned long long pk;
            do {
                pk = atomicAdd(&slots[t], 0ULL);    // device-scope atomic read
            } while ((unsigned)(pk >> 32) != ((unsigned)pk ^ MAGIC));
            x = __uint_as_float((unsigned)pk);
        }
        #pragma unroll
        for (int off = 32; off > 0; off >>= 1) x += __shfl_down(x, off);
        if (t == 0) out[0] = -x / (float)BB;
    }
}

extern "C" void kernel_launch(void* const* d_in, const int* in_sizes, int n_in,
                              void* d_out, int out_size, void* d_ws, size_t ws_size,
                              hipStream_t stream) {
    const float* scores = (const float*)d_in[0];
    const float* labels = (const float*)d_in[1];
    float* out = (float*)d_out;
    unsigned long long* slots = (unsigned long long*)d_ws;

    lfl_fused<<<BB, NT, 0, stream>>>(scores, labels, out, slots);
}